// Round 4
// baseline (683.107 us; speedup 1.0000x reference)
//
#include <hip/hip_runtime.h>

// B=8, C=64, D=8 (q/k), H=W=128.  dwconv3x3 -> CCA -> CCA -> pointwise.
// Round 9 (resubmit; rounds 1 and 3 lost to GPU acquisition timeouts):
// ONE persistent kernel.  Evidence: no single kernel >41us yet wall
// was 214us vs ~120us modeled in-kernel work => ~12-14us per dispatch
// boundary.  All 7 dispatches fused; 5 device-scope grid barriers
// (threadfence + AGENT atomics, XCD-safe) replace the launch gaps.  Phases
// grid-stride over the old block decompositions; LDS (40448B = ccdir layout)
// is aliased by every phase; __launch_bounds__(256,4) + occupancy-clamped
// grid (<=1024 blocks = 4/CU by LDS) guarantees co-residency.
// Fragment layouts (mfma_f32_16x16x32_bf16):
//   A[m=lane&15][k=quad*8+j (+32s)], B[k][n=lane&15], C col=lane&15,row=quad*4+reg
// (mfma_f32_16x16x16bf16_1k): A[m=lane&15][k=quad*4+j], B[k=quad*4+j][n=lane&15]

#define NEGINF -3.0e38f

typedef __attribute__((ext_vector_type(8))) __bf16 bf8;
typedef __attribute__((ext_vector_type(4))) __bf16 bf4;
typedef __attribute__((ext_vector_type(4))) short s4;
typedef __attribute__((ext_vector_type(4))) float f4;

__device__ __forceinline__ f4 MFMA(bf8 a, bf8 b, f4 c) {
  return __builtin_amdgcn_mfma_f32_16x16x32_bf16(a, b, c, 0, 0, 0);
}
__device__ __forceinline__ f4 MFMA16(bf4 a, bf4 b, f4 c) {
  return __builtin_amdgcn_mfma_f32_16x16x16bf16_1k(*(s4*)&a, *(s4*)&b, c, 0, 0, 0);
}
__device__ __forceinline__ ushort bfb(float f) {
  __bf16 h = (__bf16)f;
  return *(ushort*)&h;
}

struct GB { unsigned int cnt; unsigned int gen; };

// Device-scope sense-reversing grid barrier.  tid0 arrives; release fence
// (L2 writeback) before arrive, acquire fence (L2 inv) after depart, so
// ordinary stores are cross-XCD visible (Guideline 16 pattern).
__device__ __forceinline__ void gridbar(GB* gb) {
  __syncthreads();
  if (threadIdx.x == 0) {
    unsigned int g = __hip_atomic_load(&gb->gen, __ATOMIC_RELAXED,
                                       __HIP_MEMORY_SCOPE_AGENT);
    __threadfence();
    unsigned int a = __hip_atomic_fetch_add(&gb->cnt, 1u, __ATOMIC_ACQ_REL,
                                            __HIP_MEMORY_SCOPE_AGENT);
    if (a == gridDim.x - 1) {
      __hip_atomic_store(&gb->cnt, 0u, __ATOMIC_RELAXED,
                         __HIP_MEMORY_SCOPE_AGENT);
      __hip_atomic_fetch_add(&gb->gen, 1u, __ATOMIC_RELEASE,
                             __HIP_MEMORY_SCOPE_AGENT);
    } else {
      while (__hip_atomic_load(&gb->gen, __ATOMIC_RELAXED,
                               __HIP_MEMORY_SCOPE_AGENT) == g)
        __builtin_amdgcn_s_sleep(1);
    }
    __threadfence();
  }
  __syncthreads();
}

__global__ __launch_bounds__(256, 4) void fused_kernel(
    const float* __restrict__ x, const float* __restrict__ wdw,
    const float* __restrict__ wq, const float* __restrict__ wk,
    const float* __restrict__ wv, const float* __restrict__ gammap,
    const float* __restrict__ wpw,
    __bf16* __restrict__ y, __bf16* __restrict__ z, __bf16* __restrict__ AT,
    __bf16* __restrict__ wtab, __bf16* __restrict__ ptab,
    float* __restrict__ sW, float* __restrict__ sH,
    float* __restrict__ out, GB* gb) {
  __shared__ __align__(16) char smem[40448];
  int t = threadIdx.x;

  // ---- prep (block 0, lanes 0-63); consumed after gridbar #1 ----
  if (blockIdx.x == 0 && t < 64) {
    int lane = t, l16 = lane & 15, quad = lane >> 4;
    const float* wr = (l16 < 8) ? (wq + l16*64) : (wk + (l16 - 8)*64);
    for (int s = 0; s < 2; ++s)
      for (int j = 0; j < 8; ++j)
        wtab[(s*64 + lane)*8 + j] = (__bf16)wr[quad*8 + s*32 + j];
    for (int m0 = 0; m0 < 4; ++m0) {
      const float* vr = wv + (m0*16 + l16)*64;
      const float* pr = wpw + (m0*16 + l16)*64;
      for (int s = 0; s < 2; ++s)
        for (int j = 0; j < 8; ++j) {
          wtab[((2 + m0*2 + s)*64 + lane)*8 + j] = (__bf16)vr[quad*8 + s*32 + j];
          ptab[((m0*2 + s)*64 + lane)*8 + j]     = (__bf16)pr[quad*8 + s*32 + j];
        }
    }
  }

  // ---- phase DW: dwconv3x3, 32x32 tiles, writes y and yT(=AT) ----
  {
    float* in = (float*)smem;              // [34][36]
    float* ot = (float*)(smem + 4896);     // [32][33]
    int tx = t & 31, ty = t >> 5;
    for (int item = blockIdx.x; item < 8192; item += gridDim.x) {
      int w0 = (item & 3)*32, h0 = ((item >> 2) & 3)*32, n = item >> 4;
      const float* xp = x + (size_t)n*16384;
      const float* wp = wdw + (n & 63)*9;
      float wr[9];
      #pragma unroll
      for (int j = 0; j < 9; ++j) wr[j] = wp[j];
      for (int i = ty; i < 34; i += 8) {
        int hh = h0 + i - 1;
        for (int j = tx; j < 34; j += 32) {
          int ww = w0 + j - 1;
          float v = 0.f;
          if (hh >= 0 && hh < 128 && ww >= 0 && ww < 128) v = xp[hh*128 + ww];
          in[i*36 + j] = v;
        }
      }
      __syncthreads();
      for (int i2 = ty; i2 < 32; i2 += 8) {
        float acc = 0.f;
        #pragma unroll
        for (int kh = 0; kh < 3; ++kh)
          #pragma unroll
          for (int kw = 0; kw < 3; ++kw)
            acc += wr[kh*3 + kw]*in[(i2 + kh)*36 + tx + kw];
        ot[i2*33 + tx] = acc;
      }
      __syncthreads();
      ushort* yp  = (ushort*)(y  + (size_t)n*16384);
      ushort* ytp = (ushort*)(AT + (size_t)n*16384);
      for (int idx = t; idx < 512; idx += 256) {
        int row = idx >> 4, c2 = (idx & 15)*2;
        ushort2 u;
        u.x = bfb(ot[row*33 + c2]); u.y = bfb(ot[row*33 + c2 + 1]);
        *(ushort2*)&yp[(size_t)(h0 + row)*128 + w0 + c2] = u;
        ushort2 v;
        v.x = bfb(ot[c2*33 + row]); v.y = bfb(ot[(c2 + 1)*33 + row]);
        *(ushort2*)&ytp[(size_t)(w0 + row)*128 + h0 + c2] = v;
      }
      __syncthreads();                      // ot/in reuse next item
    }
  }
  gridbar(gb);                              // #1: y/AT/wtab/ptab ready

  for (int pass = 0; pass < 2; ++pass) {
    const __bf16* Abuf = pass ? z : y;      // CCA input / residual
    __bf16* Bo         = pass ? y : z;      // CCA output

    // ---- phase CC: per-row criss-cross direction (both dirs) ----
    {
      __bf16* ys = (__bf16*)smem;           // [128][72] swizzled
      __bf16* qs = (__bf16*)(smem + 18432);
      __bf16* ks = (__bf16*)(smem + 20480);
      __bf16* vs = (__bf16*)(smem + 22528); // [64][140]
      int lane = t & 63, w = t >> 6;
      int l16 = lane & 15, quad = lane >> 4;
      for (int item = blockIdx.x; item < 2048; item += gridDim.x) {
        int r = item & 127, b = (item >> 7) & 7, dir = item >> 10;
        const __bf16* src = dir ? AT : Abuf;
        __bf16* dst       = dir ? AT : Bo;
        float* so         = dir ? sH : sW;
        const ushort* sp = (const ushort*)(src + (size_t)b*1048576 + (size_t)r*128);

        // stage Y[c][p] -> ys[p][c-swizzled]
        {
          int a = t & 15, cp = t >> 4;
          ushort* yr = (ushort*)ys;
          #pragma unroll
          for (int q = 0; q < 2; ++q) {
            int c = 2*cp + 32*q;
            uint4 u0 = *(const uint4*)&sp[(size_t)c*16384 + a*8];
            uint4 u1 = *(const uint4*)&sp[(size_t)(c + 1)*16384 + a*8];
            const ushort* p0 = (const ushort*)&u0;
            const ushort* p1 = (const ushort*)&u1;
            int cx = (((c >> 3) ^ a) & 7)*8 + (c & 7);
            #pragma unroll
            for (int j = 0; j < 8; ++j) {
              ushort2 uv; uv.x = p0[j]; uv.y = p1[j];
              *(ushort2*)&yr[(a*8 + j)*72 + cx] = uv;
            }
          }
        }
        bf8 a_qk[2], a_wv[4][2];            // reload per item (keeps tail VGPR low)
        #pragma unroll
        for (int s = 0; s < 2; ++s)
          a_qk[s] = *(const bf8*)&wtab[(s*64 + lane)*8];
        #pragma unroll
        for (int m0 = 0; m0 < 4; ++m0)
          #pragma unroll
          for (int s = 0; s < 2; ++s)
            a_wv[m0][s] = *(const bf8*)&wtab[((2 + m0*2 + s)*64 + lane)*8];
        __syncthreads();                    // B0: ys staged

        // projections
        f4 z4 = {0.f, 0.f, 0.f, 0.f};
        bf8 b_ys[2][2];
        #pragma unroll
        for (int nt = 0; nt < 2; ++nt) {
          int p = w*32 + nt*16 + l16;
          int hi = (p >> 3) & 7;
          #pragma unroll
          for (int s = 0; s < 2; ++s)
            b_ys[nt][s] = *(const bf8*)&ys[p*72 + ((s*4 + quad) ^ hi)*8];
        }
        #pragma unroll
        for (int nt = 0; nt < 2; ++nt) {
          int p = w*32 + nt*16 + l16;
          f4 aqk = z4;
          aqk = MFMA(a_qk[0], b_ys[nt][0], aqk);
          aqk = MFMA(a_qk[1], b_ys[nt][1], aqk);
          __bf16* dp8 = ((quad < 2) ? qs : ks) + p*8 + (quad & 1)*4;
          #pragma unroll
          for (int rg = 0; rg < 4; ++rg) dp8[rg] = (__bf16)aqk[rg];
        }
        #pragma unroll
        for (int m0 = 0; m0 < 4; ++m0)
          #pragma unroll
          for (int nt = 0; nt < 2; ++nt) {
            f4 va = z4;
            va = MFMA(a_wv[m0][0], b_ys[nt][0], va);
            va = MFMA(a_wv[m0][1], b_ys[nt][1], va);
            int u = w*32 + nt*16 + l16;
            #pragma unroll
            for (int rg = 0; rg < 4; ++rg)
              vs[(m0*16 + quad*4 + rg)*140 + u] = (__bf16)va[rg];
          }
        __syncthreads();                    // B1: qs/ks/vs visible; ys dead

        // tail: E^T = MFMA(K,Q) -> exp in-reg -> x16 PV
        bf8 zb;
        #pragma unroll
        for (int j = 0; j < 8; ++j) zb[j] = (__bf16)0.f;
        bf8 bq[2];
        #pragma unroll
        for (int nt = 0; nt < 2; ++nt) {
          int p = w*32 + nt*16 + l16;
          bq[nt] = (quad == 0) ? *(const bf8*)&qs[p*8] : zb;
        }
        f4 acc[4][2];
        #pragma unroll
        for (int m0 = 0; m0 < 4; ++m0)
          #pragma unroll
          for (int nt = 0; nt < 2; ++nt) acc[m0][nt] = z4;
        float sm[2] = {0.f, 0.f};
        #pragma unroll
        for (int ct = 0; ct < 8; ++ct) {
          bf8 ak = (quad == 0) ? *(const bf8*)&ks[(ct*16 + l16)*8] : zb;
          bf4 av[4];
          #pragma unroll
          for (int m0 = 0; m0 < 4; ++m0)
            av[m0] = *(const bf4*)&vs[(m0*16 + l16)*140 + ct*16 + quad*4];
          #pragma unroll
          for (int nt = 0; nt < 2; ++nt) {
            f4 e = MFMA(ak, bq[nt], z4);
            if (dir) {                      // diag mask: c == p
              int pg = w*32 + nt*16 + l16, c0 = ct*16 + quad*4;
              #pragma unroll
              for (int rg = 0; rg < 4; ++rg)
                if (c0 + rg == pg) e[rg] = NEGINF;
            }
            bf4 pb;
            #pragma unroll
            for (int rg = 0; rg < 4; ++rg) {
              float pv = __expf(e[rg]);
              sm[nt] += pv;
              pb[rg] = (__bf16)pv;
            }
            #pragma unroll
            for (int m0 = 0; m0 < 4; ++m0)
              acc[m0][nt] = MFMA16(av[m0], pb, acc[m0][nt]);
          }
        }
        // stats
        int sb = ((b*128 + r) << 7);
        #pragma unroll
        for (int nt = 0; nt < 2; ++nt) {
          float s2 = sm[nt];
          s2 += __shfl_xor(s2, 16, 64);
          s2 += __shfl_xor(s2, 32, 64);
          if (quad == 0) so[sb + w*32 + nt*16 + l16] = s2;
        }
        // out-stage in own-wave slice of ys (dead post-B1)
        __bf16* oS = (__bf16*)(smem + 4608*w);   // [64][36]
        #pragma unroll
        for (int m0 = 0; m0 < 4; ++m0)
          #pragma unroll
          for (int nt = 0; nt < 2; ++nt)
            #pragma unroll
            for (int rg = 0; rg < 4; ++rg)
              oS[(m0*16 + quad*4 + rg)*36 + nt*16 + l16] = (__bf16)acc[m0][nt][rg];
        ushort* dp = (ushort*)(dst + (size_t)b*1048576 + (size_t)r*128 + w*32);
        ushort* oSu = (ushort*)oS;
        #pragma unroll
        for (int it = 0; it < 4; ++it) {
          int i = it*64 + lane;
          int d = i >> 2, ch = i & 3;
          uint2 lo  = *(const uint2*)&oSu[d*36 + ch*8];
          uint2 hi2 = *(const uint2*)&oSu[d*36 + ch*8 + 4];
          uint4 uu; uu.x = lo.x; uu.y = lo.y; uu.z = hi2.x; uu.w = hi2.y;
          *(uint4*)&dp[(size_t)d*16384 + ch*8] = uu;
        }
        __syncthreads();                    // ys reuse next item
      }
    }
    gridbar(gb);                            // CC outputs + stats ready

    // ---- phase COMB: Bo = g*(Bo + AT^T)/(sW+sH) + A; pass0 also AT=Bo^T ----
    {
      float* tile = (float*)smem;           // [32][33]
      float* ts   = (float*)(smem + 4224);  // [32][33]
      float* rt   = (float*)(smem + 8448);  // [32][33]
      int tx = t & 15, ty = t >> 4;
      float g = gammap[0];
      int writeT = (pass == 0) ? 1 : 0;
      for (int item = blockIdx.x; item < 8192; item += gridDim.x) {
        int x0 = (item & 3)*32, y0 = ((item >> 2) & 3)*32, n = item >> 4;
        int b = n >> 6;
        const ushort* ip = (const ushort*)(AT + (size_t)n*16384);
        const float* shp = sH + b*16384;
        for (int i = ty; i < 32; i += 16) {
          ushort2 u = *(const ushort2*)&ip[(size_t)(y0 + i)*128 + x0 + 2*tx];
          tile[i*33 + 2*tx]     = (float)*(__bf16*)&u.x;
          tile[i*33 + 2*tx + 1] = (float)*(__bf16*)&u.y;
          float2 s2 = *(const float2*)&shp[(y0 + i)*128 + x0 + 2*tx];
          ts[i*33 + 2*tx] = s2.x; ts[i*33 + 2*tx + 1] = s2.y;
        }
        __syncthreads();
        for (int i2 = ty; i2 < 32; i2 += 16) {
          int h = x0 + i2, w2 = y0 + 2*tx;
          size_t idx = (size_t)n*16384 + (size_t)h*128 + w2;
          int pix = b*16384 + h*128 + w2;
          float2 swv = *(const float2*)&sW[pix];
          ushort2 bo = *(const ushort2*)((const ushort*)Bo + idx);
          ushort2 aa = *(const ushort2*)((const ushort*)Abuf + idx);
          float inv0 = 1.0f/(swv.x + ts[(2*tx)*33 + i2]);
          float r0 = g*((float)*(__bf16*)&bo.x + tile[(2*tx)*33 + i2])*inv0
                     + (float)*(__bf16*)&aa.x;
          float inv1 = 1.0f/(swv.y + ts[(2*tx + 1)*33 + i2]);
          float r1 = g*((float)*(__bf16*)&bo.y + tile[(2*tx + 1)*33 + i2])*inv1
                     + (float)*(__bf16*)&aa.y;
          ushort2 o; o.x = bfb(r0); o.y = bfb(r1);
          *(ushort2*)((ushort*)Bo + idx) = o;
          rt[i2*33 + 2*tx] = r0; rt[i2*33 + 2*tx + 1] = r1;
        }
        if (writeT) {
          __syncthreads();
          for (int i = ty; i < 32; i += 16) {
            ushort2 o;
            o.x = bfb(rt[(2*tx)*33 + i]); o.y = bfb(rt[(2*tx + 1)*33 + i]);
            *(ushort2*)((ushort*)AT + (size_t)n*16384 +
                        (size_t)(y0 + i)*128 + x0 + 2*tx) = o;
          }
        }
        __syncthreads();                    // tile/ts/rt reuse next item
      }
    }
    gridbar(gb);                            // combined planes ready
  }

  // ---- phase PW: out[o][p] = sum_c wpw[o][c]*y[c][p] (fp32 out) ----
  {
    __bf16* ys = (__bf16*)smem;             // [128][72] swizzled
    int lane = t & 63, w = t >> 6;
    int l16 = lane & 15, quad = lane >> 4;
    for (int item = blockIdx.x; item < 1024; item += gridDim.x) {
      int r = item & 127, b = item >> 7;
      const ushort* sp = (const ushort*)(y + (size_t)b*1048576 + (size_t)r*128);
      {
        int a = t & 15, cp = t >> 4;
        ushort* yr = (ushort*)ys;
        #pragma unroll
        for (int q = 0; q < 2; ++q) {
          int c = 2*cp + 32*q;
          uint4 u0 = *(const uint4*)&sp[(size_t)c*16384 + a*8];
          uint4 u1 = *(const uint4*)&sp[(size_t)(c + 1)*16384 + a*8];
          const ushort* p0 = (const ushort*)&u0;
          const ushort* p1 = (const ushort*)&u1;
          int cx = (((c >> 3) ^ a) & 7)*8 + (c & 7);
          #pragma unroll
          for (int j = 0; j < 8; ++j) {
            ushort2 uv; uv.x = p0[j]; uv.y = p1[j];
            *(ushort2*)&yr[(a*8 + j)*72 + cx] = uv;
          }
        }
      }
      bf8 a_w[4][2];
      #pragma unroll
      for (int m0 = 0; m0 < 4; ++m0)
        #pragma unroll
        for (int s = 0; s < 2; ++s)
          a_w[m0][s] = *(const bf8*)&ptab[((m0*2 + s)*64 + lane)*8];
      __syncthreads();                      // ys staged
      bf8 b_ys[2][2];
      #pragma unroll
      for (int nt = 0; nt < 2; ++nt) {
        int p = w*32 + nt*16 + l16;
        int hi = (p >> 3) & 7;
        #pragma unroll
        for (int s = 0; s < 2; ++s)
          b_ys[nt][s] = *(const bf8*)&ys[p*72 + ((s*4 + quad) ^ hi)*8];
      }
      __syncthreads();                      // frag loads done; ys dead
      f4 z4 = {0.f, 0.f, 0.f, 0.f};
      f4 acc[4][2];
      #pragma unroll
      for (int m0 = 0; m0 < 4; ++m0)
        #pragma unroll
        for (int nt = 0; nt < 2; ++nt) {
          f4 a2 = z4;
          a2 = MFMA(a_w[m0][0], b_ys[nt][0], a2);
          a2 = MFMA(a_w[m0][1], b_ys[nt][1], a2);
          acc[m0][nt] = a2;
        }
      float* oS = (float*)(smem + 9216*w);  // [64][36] fp32, wave-local
      #pragma unroll
      for (int m0 = 0; m0 < 4; ++m0)
        #pragma unroll
        for (int nt = 0; nt < 2; ++nt)
          #pragma unroll
          for (int rg = 0; rg < 4; ++rg)
            oS[(m0*16 + quad*4 + rg)*36 + nt*16 + l16] = acc[m0][nt][rg];
      float* dp = out + (size_t)b*1048576 + (size_t)r*128 + w*32;
      #pragma unroll
      for (int it = 0; it < 8; ++it) {
        int i = it*64 + lane;
        int d = i >> 3, p4 = i & 7;
        f4 v = *(const f4*)&oS[d*36 + p4*4];
        *(f4*)&dp[(size_t)d*16384 + p4*4] = v;
      }
      __syncthreads();                      // ys reuse next item
    }
  }
}

extern "C" void kernel_launch(void* const* d_in, const int* in_sizes, int n_in,
                              void* d_out, int out_size, void* d_ws, size_t ws_size,
                              hipStream_t stream) {
  const float* x     = (const float*)d_in[0];
  const float* wdw   = (const float*)d_in[1];
  const float* wq    = (const float*)d_in[2];
  const float* wk    = (const float*)d_in[3];
  const float* wv    = (const float*)d_in[4];
  const float* gamma = (const float*)d_in[5];
  const float* wpw   = (const float*)d_in[6];
  float* out = (float*)d_out;

  // Workspace: y,z,AT bf16 (16 MB each) + wtab/ptab + 2 fp32 stat planes + barrier.
  __bf16* y    = (__bf16*)d_ws;
  __bf16* z    = y + 8388608;
  __bf16* AT   = z + 8388608;
  __bf16* wtab = AT + 8388608;        // 10 frags x 64 lanes x 8 = 5120
  __bf16* ptab = wtab + 5120;         // 8 frags x 64 lanes x 8 = 4096
  float* sW = (float*)(ptab + 4096);
  float* sH = sW + 131072;
  GB* gb = (GB*)(sH + 131072);
  size_t need = (size_t)3*8388608*2 + (5120 + 4096)*2 + (size_t)2*131072*4 + 256;
  if (ws_size < need) return;

  static int nblocks = 0;
  if (nblocks == 0) {
    int occ = 0;
    hipError_t e = hipOccupancyMaxActiveBlocksPerMultiprocessor(
        &occ, (const void*)fused_kernel, 256, 0);
    if (e != hipSuccess || occ < 1) occ = 2;   // conservative fallback
    if (occ > 4) occ = 4;                      // LDS bound: 4/CU max
    nblocks = occ * 256;                       // 256 CUs on MI355X
  }

  hipMemsetAsync(gb, 0, sizeof(GB), stream);
  fused_kernel<<<dim3(nblocks), dim3(256), 0, stream>>>(
      x, wdw, wq, wk, wv, gamma, wpw, y, z, AT, wtab, ptab, sW, sH, out, gb);
}

// Round 5
// 205.286 us; speedup vs baseline: 3.3276x; 3.3276x over previous
//
#include <hip/hip_runtime.h>

// B=8, C=64, D=8 (q/k), H=W=128.  dwconv3x3 -> CCA -> CCA -> pointwise.
// Round 10: REVERT the persistent-kernel fusion (r9: 683us vs 214us —
// per-block agent-scope fences at grid barriers = L2 flush/inv storms,
// GPU 95% idle).  Back to the r8 split kernels (214.6us) plus:
//   (a) prep_weights folded into dwconv block (0,0,0) — one fewer launch;
//   (b) E-step switched to mfma_f32_16x16x16bf16_1k (quads 0-1 carry
//       k=0..7) — halves qs/ks LDS reads vs the quarter-utilized x32 form.
// Fragment layouts (mfma_f32_16x16x32_bf16):
//   A[m=lane&15][k=quad*8+j (+32s)], B[k][n=lane&15], C col=lane&15,row=quad*4+reg
// (mfma_f32_16x16x16bf16_1k): A[m=lane&15][k=quad*4+j], B[k=quad*4+j][n=lane&15],
//   C col=lane&15,row=quad*4+reg (shape-determined, same as x32).

#define NEGINF -3.0e38f

typedef __attribute__((ext_vector_type(8))) __bf16 bf8;
typedef __attribute__((ext_vector_type(4))) __bf16 bf4;
typedef __attribute__((ext_vector_type(4))) short s4;
typedef __attribute__((ext_vector_type(4))) float f4;

__device__ __forceinline__ f4 MFMA(bf8 a, bf8 b, f4 c) {
  return __builtin_amdgcn_mfma_f32_16x16x32_bf16(a, b, c, 0, 0, 0);
}
__device__ __forceinline__ f4 MFMA16(bf4 a, bf4 b, f4 c) {
  return __builtin_amdgcn_mfma_f32_16x16x16bf16_1k(*(s4*)&a, *(s4*)&b, c, 0, 0, 0);
}
__device__ __forceinline__ ushort bfb(float f) {
  __bf16 h = (__bf16)f;
  return *(ushort*)&h;
}

// 32x32-tile dwconv3x3; writes y and yT (bf16), packed ushort2 stores.
// Block (0,0,0) lanes 0-63 also pack the weight-fragment tables (consumed
// by the NEXT launch; stream ordering guarantees visibility).
__global__ __launch_bounds__(256) void dwconv_kernel(
    const float* __restrict__ x, const float* __restrict__ wdw,
    __bf16* __restrict__ y, __bf16* __restrict__ yT,
    const float* __restrict__ wq, const float* __restrict__ wk,
    const float* __restrict__ wv, const float* __restrict__ wpw,
    __bf16* __restrict__ wtab, __bf16* __restrict__ ptab) {
  __shared__ float in[34][36];
  __shared__ float ot[32][33];
  if (blockIdx.x == 0 && blockIdx.y == 0 && blockIdx.z == 0 &&
      threadIdx.x < 64) {
    int lane = threadIdx.x;
    int l16 = lane & 15, quad = lane >> 4;
    const float* wr = (l16 < 8) ? (wq + l16*64) : (wk + (l16 - 8)*64);
    for (int s = 0; s < 2; ++s)
      for (int j = 0; j < 8; ++j)
        wtab[(s*64 + lane)*8 + j] = (__bf16)wr[quad*8 + s*32 + j];
    for (int m0 = 0; m0 < 4; ++m0) {
      const float* vr = wv + (m0*16 + l16)*64;
      const float* pr = wpw + (m0*16 + l16)*64;
      for (int s = 0; s < 2; ++s)
        for (int j = 0; j < 8; ++j) {
          wtab[((2 + m0*2 + s)*64 + lane)*8 + j] = (__bf16)vr[quad*8 + s*32 + j];
          ptab[((m0*2 + s)*64 + lane)*8 + j]     = (__bf16)pr[quad*8 + s*32 + j];
        }
    }
  }
  int tx = threadIdx.x & 31, ty = threadIdx.x >> 5;   // 32x8
  int w0 = blockIdx.x*32, h0 = blockIdx.y*32;
  int n = blockIdx.z;                                  // b*64 + c
  const float* xp = x + (size_t)n*16384;
  const float* wp = wdw + (n & 63)*9;
  float wr[9];
  #pragma unroll
  for (int j = 0; j < 9; ++j) wr[j] = wp[j];
  for (int i = ty; i < 34; i += 8) {
    int hh = h0 + i - 1;
    for (int j = tx; j < 34; j += 32) {
      int ww = w0 + j - 1;
      float v = 0.f;
      if (hh >= 0 && hh < 128 && ww >= 0 && ww < 128) v = xp[hh*128 + ww];
      in[i][j] = v;
    }
  }
  __syncthreads();
  for (int i2 = ty; i2 < 32; i2 += 8) {
    float acc = 0.f;
    #pragma unroll
    for (int kh = 0; kh < 3; ++kh)
      #pragma unroll
      for (int kw = 0; kw < 3; ++kw)
        acc += wr[kh*3 + kw]*in[i2 + kh][tx + kw];
    ot[i2][tx] = acc;
  }
  __syncthreads();
  ushort* yp  = (ushort*)(y  + (size_t)n*16384);
  ushort* ytp = (ushort*)(yT + (size_t)n*16384);
  for (int idx = threadIdx.x; idx < 512; idx += 256) {
    int row = idx >> 4, c2 = (idx & 15)*2;
    ushort2 u;
    u.x = bfb(ot[row][c2]); u.y = bfb(ot[row][c2 + 1]);
    *(ushort2*)&yp[(size_t)(h0 + row)*128 + w0 + c2] = u;
    ushort2 v;
    v.x = bfb(ot[c2][row]); v.y = bfb(ot[c2 + 1][row]);
    *(ushort2*)&ytp[(size_t)(w0 + row)*128 + h0 + c2] = v;
  }
}

// Fused CCA direction kernel, two barriers, no max-subtract.
// dir=0: src=A -> dstRow, stats sW.  dir=1: src=dst=AT in place, diag mask,
// stats sH.  Output UNNORMALIZED: O[d][p] = sum_c exp(e(p,c)) * v[d][c].
__global__ __launch_bounds__(256) void ccdir_kernel(
    const __bf16* __restrict__ srcRow, __bf16* __restrict__ dstRow,
    __bf16* __restrict__ srcdstCol,
    const __bf16* __restrict__ wtab,
    float* __restrict__ sW, float* __restrict__ sH) {
  // LDS: ys[128][72]b16 (XOR-swizzled chunks) @0 (18432; per-wave out-stage
  // [64][36]b16 = 4608 B aliases it post-B1); qs[128][8] @18432;
  // ks[128][8] @20480; vs[64][140] @22528 (17920).
  // Total 40448 -> 4 blocks/CU.
  __shared__ __align__(16) char smem[40448];
  __bf16* ys = (__bf16*)smem;
  __bf16* qs = (__bf16*)(smem + 18432);
  __bf16* ks = (__bf16*)(smem + 20480);
  __bf16* vs = (__bf16*)(smem + 22528);

  int t = threadIdx.x;
  int r = blockIdx.x, b = blockIdx.y, dir = blockIdx.z;
  const __bf16* src = dir ? srcdstCol : srcRow;
  __bf16* dst       = dir ? srcdstCol : dstRow;
  float* so         = dir ? sH : sW;
  const ushort* sp = (const ushort*)(src + (size_t)b*1048576 + (size_t)r*128);

  int lane = t & 63, w = t >> 6;
  int l16 = lane & 15, quad = lane >> 4;

  // ---- phase 0: stage Y[c][p] -> ys[p][c-swizzled] + weight frags ----
  {
    int a = t & 15, cp = t >> 4;          // p0 = a*8; channel pair 2cp(+32q)
    ushort* yr = (ushort*)ys;
    #pragma unroll
    for (int q = 0; q < 2; ++q) {
      int c = 2*cp + 32*q;
      uint4 u0 = *(const uint4*)&sp[(size_t)c*16384 + a*8];
      uint4 u1 = *(const uint4*)&sp[(size_t)(c + 1)*16384 + a*8];
      const ushort* p0 = (const ushort*)&u0;
      const ushort* p1 = (const ushort*)&u1;
      int cx = (((c >> 3) ^ a) & 7)*8 + (c & 7);   // swizzle by (p>>3)&7 == a&7
      #pragma unroll
      for (int j = 0; j < 8; ++j) {
        ushort2 uv; uv.x = p0[j]; uv.y = p1[j];
        *(ushort2*)&yr[(a*8 + j)*72 + cx] = uv;
      }
    }
  }
  bf8 a_qk[2], a_wv[4][2];
  #pragma unroll
  for (int s = 0; s < 2; ++s)
    a_qk[s] = *(const bf8*)&wtab[(s*64 + lane)*8];
  #pragma unroll
  for (int m0 = 0; m0 < 4; ++m0)
    #pragma unroll
    for (int s = 0; s < 2; ++s)
      a_wv[m0][s] = *(const bf8*)&wtab[((2 + m0*2 + s)*64 + lane)*8];
  __syncthreads();                      // B0: ys staged

  // ---- phase 1: projections (wave owns p-block [32w, 32w+32)) ----
  f4 z4 = {0.f, 0.f, 0.f, 0.f};
  bf8 b_ys[2][2];
  #pragma unroll
  for (int nt = 0; nt < 2; ++nt) {
    int p = w*32 + nt*16 + l16;
    int hi = (p >> 3) & 7;
    #pragma unroll
    for (int s = 0; s < 2; ++s)
      b_ys[nt][s] = *(const bf8*)&ys[p*72 + ((s*4 + quad) ^ hi)*8];
  }
  #pragma unroll
  for (int nt = 0; nt < 2; ++nt) {
    int p = w*32 + nt*16 + l16;
    f4 aqk = z4;
    aqk = MFMA(a_qk[0], b_ys[nt][0], aqk);
    aqk = MFMA(a_qk[1], b_ys[nt][1], aqk);
    __bf16* dp8 = ((quad < 2) ? qs : ks) + p*8 + (quad & 1)*4;
    #pragma unroll
    for (int rg = 0; rg < 4; ++rg) dp8[rg] = (__bf16)aqk[rg];
  }
  #pragma unroll
  for (int m0 = 0; m0 < 4; ++m0)
    #pragma unroll
    for (int nt = 0; nt < 2; ++nt) {
      f4 va = z4;
      va = MFMA(a_wv[m0][0], b_ys[nt][0], va);
      va = MFMA(a_wv[m0][1], b_ys[nt][1], va);
      int u = w*32 + nt*16 + l16;
      #pragma unroll
      for (int rg = 0; rg < 4; ++rg)
        vs[(m0*16 + quad*4 + rg)*140 + u] = (__bf16)va[rg];
    }
  __syncthreads();                      // B1: qs/ks/vs visible; ys dead

  // ---- barrier-free tail: E^T = MFMA16(K,Q) -> exp in-reg -> x16 PV ----
  // E^T via 16x16x16: A[m=c][k=quad*4+j] (quads 0-1 carry k=0..7),
  // B[k][n=p=l16].  C-layout: lane holds E[p=l16][c=quad*4+rg] == B-frag of
  // the PV x16 MFMA, so P feeds PV directly from registers.
  bf4 zb4;
  #pragma unroll
  for (int j = 0; j < 4; ++j) zb4[j] = (__bf16)0.f;
  bf4 bq[2];
  #pragma unroll
  for (int nt = 0; nt < 2; ++nt) {
    int p = w*32 + nt*16 + l16;
    bq[nt] = (quad < 2) ? *(const bf4*)&qs[p*8 + quad*4] : zb4;
  }
  f4 acc[4][2];
  #pragma unroll
  for (int m0 = 0; m0 < 4; ++m0)
    #pragma unroll
    for (int nt = 0; nt < 2; ++nt) acc[m0][nt] = z4;
  float sm[2] = {0.f, 0.f};

  #pragma unroll
  for (int ct = 0; ct < 8; ++ct) {
    bf4 ak = (quad < 2) ? *(const bf4*)&ks[(ct*16 + l16)*8 + quad*4] : zb4;
    bf4 av[4];
    #pragma unroll
    for (int m0 = 0; m0 < 4; ++m0)
      av[m0] = *(const bf4*)&vs[(m0*16 + l16)*140 + ct*16 + quad*4];
    #pragma unroll
    for (int nt = 0; nt < 2; ++nt) {
      f4 e = MFMA16(ak, bq[nt], z4);
      if (dir) {                        // diag mask: c == p
        int pg = w*32 + nt*16 + l16, c0 = ct*16 + quad*4;
        #pragma unroll
        for (int rg = 0; rg < 4; ++rg)
          if (c0 + rg == pg) e[rg] = NEGINF;
      }
      bf4 pb;
      #pragma unroll
      for (int rg = 0; rg < 4; ++rg) {
        float pv = __expf(e[rg]);
        sm[nt] += pv;
        pb[rg] = (__bf16)pv;
      }
      #pragma unroll
      for (int m0 = 0; m0 < 4; ++m0)
        acc[m0][nt] = MFMA16(av[m0], pb, acc[m0][nt]);
    }
  }

  // stats: lane holds partial S[p=l16] over c = quad*4+rg (+16ct); reduce quads
  int sb = ((b*128 + r) << 7);
  #pragma unroll
  for (int nt = 0; nt < 2; ++nt) {
    float s2 = sm[nt];
    s2 += __shfl_xor(s2, 16, 64);
    s2 += __shfl_xor(s2, 32, 64);
    if (quad == 0) so[sb + w*32 + nt*16 + l16] = s2;
  }

  // out-stage in own-wave slice of ys (wave-private; post-B1 so ys is dead)
  __bf16* oS = (__bf16*)(smem + 4608*w);   // [64][36] bf16
  #pragma unroll
  for (int m0 = 0; m0 < 4; ++m0)
    #pragma unroll
    for (int nt = 0; nt < 2; ++nt)
      #pragma unroll
      for (int rg = 0; rg < 4; ++rg)
        oS[(m0*16 + quad*4 + rg)*36 + nt*16 + l16] = (__bf16)acc[m0][nt][rg];
  ushort* dp = (ushort*)(dst + (size_t)b*1048576 + (size_t)r*128 + w*32);
  ushort* oSu = (ushort*)oS;
  #pragma unroll
  for (int it = 0; it < 4; ++it) {
    int i = it*64 + lane;
    int d = i >> 2, ch = i & 3;
    uint2 lo  = *(const uint2*)&oSu[d*36 + ch*8];
    uint2 hi2 = *(const uint2*)&oSu[d*36 + ch*8 + 4];
    uint4 uu; uu.x = lo.x; uu.y = lo.y; uu.z = hi2.x; uu.w = hi2.y;
    *(uint4*)&dp[(size_t)d*16384 + ch*8] = uu;
  }
}

// Fused scale+combine:  Bo = gamma*(Bo + oT^T)/(sW+sH) + A.  Optionally
// writes Bo^T into BoT (may alias oT; tile staged to LDS first).
// 16x16 threads, 2-wide x (ushort2/float2 traffic).
__global__ __launch_bounds__(256) void combineT_kernel(
    __bf16* __restrict__ Bo, const __bf16* oT,
    const __bf16* __restrict__ A,
    const float* __restrict__ sW, const float* __restrict__ sH,
    const float* __restrict__ gamma, __bf16* BoT, int writeT) {
  __shared__ float tile[32][33], ts[32][33];
  __shared__ float rt[32][33];
  int tx = threadIdx.x, ty = threadIdx.y;       // 16x16
  int n = blockIdx.z;                           // b*64 + d
  int b = n >> 6;
  int x0 = blockIdx.x*32, y0 = blockIdx.y*32;
  const ushort* ip = (const ushort*)(oT + (size_t)n*16384);
  const float* shp = sH + b*16384;
  for (int i = ty; i < 32; i += 16) {
    ushort2 u = *(const ushort2*)&ip[(size_t)(y0 + i)*128 + x0 + 2*tx];
    tile[i][2*tx]     = (float)*(__bf16*)&u.x;
    tile[i][2*tx + 1] = (float)*(__bf16*)&u.y;
    float2 s2 = *(const float2*)&shp[(y0 + i)*128 + x0 + 2*tx];
    ts[i][2*tx] = s2.x; ts[i][2*tx + 1] = s2.y;
  }
  __syncthreads();
  float g = *gamma;
  for (int i2 = ty; i2 < 32; i2 += 16) {
    int h = x0 + i2, w2 = y0 + 2*tx;
    size_t idx = (size_t)n*16384 + (size_t)h*128 + w2;
    int pix = b*16384 + h*128 + w2;
    float2 swv = *(const float2*)&sW[pix];
    ushort2 bo = *(const ushort2*)((const ushort*)Bo + idx);
    ushort2 aa = *(const ushort2*)((const ushort*)A + idx);
    float inv0 = 1.0f/(swv.x + ts[2*tx][i2]);
    float r0 = g*((float)*(__bf16*)&bo.x + tile[2*tx][i2])*inv0
               + (float)*(__bf16*)&aa.x;
    float inv1 = 1.0f/(swv.y + ts[2*tx + 1][i2]);
    float r1 = g*((float)*(__bf16*)&bo.y + tile[2*tx + 1][i2])*inv1
               + (float)*(__bf16*)&aa.y;
    ushort2 o; o.x = bfb(r0); o.y = bfb(r1);
    *(ushort2*)((ushort*)Bo + idx) = o;
    rt[i2][2*tx] = r0; rt[i2][2*tx + 1] = r1;
  }
  if (writeT) {
    __syncthreads();
    for (int i = ty; i < 32; i += 16) {
      ushort2 o;
      o.x = bfb(rt[2*tx][i]); o.y = bfb(rt[2*tx + 1][i]);
      *(ushort2*)((ushort*)BoT + (size_t)n*16384 +
                  (size_t)(y0 + i)*128 + x0 + 2*tx) = o;
    }
  }
}

// MFMA pointwise 64->64 per (b,r) slice: out[o][p] = sum_c wpw[o][c]*A[c][p].
__global__ __launch_bounds__(256) void pw_kernel(
    const __bf16* __restrict__ A, const __bf16* __restrict__ ptab,
    float* __restrict__ out) {
  // ys[128][72] swizzled @0 (18432); out-stage [64][36]f32/wave (9216) alias.
  __shared__ __align__(16) char smem[36864];
  __bf16* ys = (__bf16*)smem;
  int t = threadIdx.x;
  int r = blockIdx.x, b = blockIdx.y;
  const ushort* sp = (const ushort*)(A + (size_t)b*1048576 + (size_t)r*128);
  {
    int a = t & 15, cp = t >> 4;
    ushort* yr = (ushort*)ys;
    #pragma unroll
    for (int q = 0; q < 2; ++q) {
      int c = 2*cp + 32*q;
      uint4 u0 = *(const uint4*)&sp[(size_t)c*16384 + a*8];
      uint4 u1 = *(const uint4*)&sp[(size_t)(c + 1)*16384 + a*8];
      const ushort* p0 = (const ushort*)&u0;
      const ushort* p1 = (const ushort*)&u1;
      int cx = (((c >> 3) ^ a) & 7)*8 + (c & 7);
      #pragma unroll
      for (int j = 0; j < 8; ++j) {
        ushort2 uv; uv.x = p0[j]; uv.y = p1[j];
        *(ushort2*)&yr[(a*8 + j)*72 + cx] = uv;
      }
    }
  }
  int lane = t & 63, w = t >> 6;
  int l16 = lane & 15, quad = lane >> 4;
  bf8 a_w[4][2];
  #pragma unroll
  for (int m0 = 0; m0 < 4; ++m0)
    #pragma unroll
    for (int s = 0; s < 2; ++s)
      a_w[m0][s] = *(const bf8*)&ptab[((m0*2 + s)*64 + lane)*8];
  __syncthreads();                     // ys staged
  bf8 b_ys[2][2];
  #pragma unroll
  for (int nt = 0; nt < 2; ++nt) {
    int p = w*32 + nt*16 + l16;
    int hi = (p >> 3) & 7;
    #pragma unroll
    for (int s = 0; s < 2; ++s)
      b_ys[nt][s] = *(const bf8*)&ys[p*72 + ((s*4 + quad) ^ hi)*8];
  }
  __syncthreads();                     // all frag loads done; ys dead
  f4 z4 = {0.f, 0.f, 0.f, 0.f};
  f4 acc[4][2];
  #pragma unroll
  for (int m0 = 0; m0 < 4; ++m0)
    #pragma unroll
    for (int nt = 0; nt < 2; ++nt) {
      f4 a2 = z4;
      a2 = MFMA(a_w[m0][0], b_ys[nt][0], a2);
      a2 = MFMA(a_w[m0][1], b_ys[nt][1], a2);
      acc[m0][nt] = a2;
    }
  float* oS = (float*)(smem + 9216*w);  // [64][36] fp32, wave-local
  #pragma unroll
  for (int m0 = 0; m0 < 4; ++m0)
    #pragma unroll
    for (int nt = 0; nt < 2; ++nt)
      #pragma unroll
      for (int rg = 0; rg < 4; ++rg)
        oS[(m0*16 + quad*4 + rg)*36 + nt*16 + l16] = acc[m0][nt][rg];
  float* dp = out + (size_t)b*1048576 + (size_t)r*128 + w*32;
  #pragma unroll
  for (int it = 0; it < 8; ++it) {
    int i = it*64 + lane;
    int d = i >> 3, p4 = i & 7;
    f4 v = *(const f4*)&oS[d*36 + p4*4];
    *(f4*)&dp[(size_t)d*16384 + p4*4] = v;
  }
}

extern "C" void kernel_launch(void* const* d_in, const int* in_sizes, int n_in,
                              void* d_out, int out_size, void* d_ws, size_t ws_size,
                              hipStream_t stream) {
  const float* x     = (const float*)d_in[0];
  const float* wdw   = (const float*)d_in[1];
  const float* wq    = (const float*)d_in[2];
  const float* wk    = (const float*)d_in[3];
  const float* wv    = (const float*)d_in[4];
  const float* gamma = (const float*)d_in[5];
  const float* wpw   = (const float*)d_in[6];
  float* out = (float*)d_out;

  // Workspace: y,z,AT bf16 (16 MB each) + wtab/ptab + 2 fp32 stat planes.
  __bf16* y    = (__bf16*)d_ws;
  __bf16* z    = y + 8388608;
  __bf16* AT   = z + 8388608;
  __bf16* wtab = AT + 8388608;        // 10 frags x 64 lanes x 8 = 5120
  __bf16* ptab = wtab + 5120;         // 8 frags x 64 lanes x 8 = 4096
  float* sW = (float*)(ptab + 4096);
  float* sH = sW + 131072;
  size_t need = (size_t)3*8388608*2 + (5120 + 4096)*2 + (size_t)2*131072*4;
  if (ws_size < need) return;

  dwconv_kernel<<<dim3(4, 4, 512), 256, 0, stream>>>(
      x, wdw, y, AT, wq, wk, wv, wpw, wtab, ptab);

  for (int pass = 0; pass < 2; ++pass) {
    const __bf16* A = pass ? z : y;   // CCA input / residual
    __bf16* Bo      = pass ? y : z;   // CCA output

    ccdir_kernel<<<dim3(128, 8, 2), 256, 0, stream>>>(
        A, Bo, AT, wtab, sW, sH);
    // pass 0: also write Bo^T into AT (next pass's transposed input)
    combineT_kernel<<<dim3(4, 4, 512), dim3(16, 16), 0, stream>>>(
        Bo, AT, A, sW, sH, gamma, AT, pass == 0 ? 1 : 0);
  }

  pw_kernel<<<dim3(128, 8), 256, 0, stream>>>(y, ptab, out);
}

// Round 6
// 203.380 us; speedup vs baseline: 3.3588x; 1.0094x over previous
//
#include <hip/hip_runtime.h>

// B=8, C=64, D=8 (q/k), H=W=128.  dwconv3x3 -> CCA -> CCA -> pointwise.
// Round 11 (base r10 = 205.3us): operand-order algebra to linearize LDS
// scatters + misc trims:
//  (1) V-proj swapped MFMA(b_ys,a_wv) -> C-layout p-major -> vs writes are
//      8 b64 instead of 32 scalar b16 (+cvt_pk-able).
//  (2) Q kept in registers (proj C-layout == E-step B-frag for quads 0-1);
//      qs LDS deleted.  ks write is one b64 (quads 2-3 only).
//  (3) PV swapped MFMA16(pb,av) -> acc p-major -> oS stage 8 b64; same
//      swap in pw -> 8 b128 f32 stores.
//  (4) wq pre-scaled by log2(e) in prep; tail uses exp2f (exact softmax
//      invariance) -- deletes 64 v_mul/thread.
//  (5) dwconv linear-index staging (~90% lane util vs ~45%).
// Fragment layouts (mfma_f32_16x16x32_bf16):
//   A[m=lane&15][k=quad*8+j (+32s)], B[k][n=lane&15], C col=lane&15,row=quad*4+reg
// (mfma_f32_16x16x16bf16_1k): A[m=lane&15][k=quad*4+j], B[k=quad*4+j][n=lane&15],
//   C col=lane&15,row=quad*4+reg.

#define NEGINF -3.0e38f

typedef __attribute__((ext_vector_type(8))) __bf16 bf8;
typedef __attribute__((ext_vector_type(4))) __bf16 bf4;
typedef __attribute__((ext_vector_type(4))) short s4;
typedef __attribute__((ext_vector_type(4))) float f4;

__device__ __forceinline__ f4 MFMA(bf8 a, bf8 b, f4 c) {
  return __builtin_amdgcn_mfma_f32_16x16x32_bf16(a, b, c, 0, 0, 0);
}
__device__ __forceinline__ f4 MFMA16(bf4 a, bf4 b, f4 c) {
  return __builtin_amdgcn_mfma_f32_16x16x16bf16_1k(*(s4*)&a, *(s4*)&b, c, 0, 0, 0);
}
__device__ __forceinline__ ushort bfb(float f) {
  __bf16 h = (__bf16)f;
  return *(ushort*)&h;
}

// 32x32-tile dwconv3x3; writes y and yT (bf16), packed ushort2 stores.
// Block (0,0,0) lanes 0-63 also pack the weight-fragment tables (consumed
// by the NEXT launch; stream ordering guarantees visibility).
__global__ __launch_bounds__(256) void dwconv_kernel(
    const float* __restrict__ x, const float* __restrict__ wdw,
    __bf16* __restrict__ y, __bf16* __restrict__ yT,
    const float* __restrict__ wq, const float* __restrict__ wk,
    const float* __restrict__ wv, const float* __restrict__ wpw,
    __bf16* __restrict__ wtab, __bf16* __restrict__ ptab) {
  __shared__ float in[34][36];
  __shared__ float ot[32][33];
  if (blockIdx.x == 0 && blockIdx.y == 0 && blockIdx.z == 0 &&
      threadIdx.x < 64) {
    int lane = threadIdx.x;
    int l16 = lane & 15, quad = lane >> 4;
    const float* wr = (l16 < 8) ? (wq + l16*64) : (wk + (l16 - 8)*64);
    float scale = (l16 < 8) ? 1.4426950408889634f : 1.0f;   // log2(e) on wq
    for (int s = 0; s < 2; ++s)
      for (int j = 0; j < 8; ++j)
        wtab[(s*64 + lane)*8 + j] = (__bf16)(wr[quad*8 + s*32 + j]*scale);
    for (int m0 = 0; m0 < 4; ++m0) {
      const float* vr = wv + (m0*16 + l16)*64;
      const float* pr = wpw + (m0*16 + l16)*64;
      for (int s = 0; s < 2; ++s)
        for (int j = 0; j < 8; ++j) {
          wtab[((2 + m0*2 + s)*64 + lane)*8 + j] = (__bf16)vr[quad*8 + s*32 + j];
          ptab[((m0*2 + s)*64 + lane)*8 + j]     = (__bf16)pr[quad*8 + s*32 + j];
        }
    }
  }
  int tx = threadIdx.x & 31, ty = threadIdx.x >> 5;   // 32x8
  int w0 = blockIdx.x*32, h0 = blockIdx.y*32;
  int n = blockIdx.z;                                  // b*64 + c
  const float* xp = x + (size_t)n*16384;
  const float* wp = wdw + (n & 63)*9;
  float wr[9];
  #pragma unroll
  for (int j = 0; j < 9; ++j) wr[j] = wp[j];
  for (int idx = threadIdx.x; idx < 1156; idx += 256) {  // 34*34 linear
    int i = idx/34, j = idx - i*34;
    int hh = h0 + i - 1, ww = w0 + j - 1;
    float v = 0.f;
    if (hh >= 0 && hh < 128 && ww >= 0 && ww < 128) v = xp[hh*128 + ww];
    in[i][j] = v;
  }
  __syncthreads();
  for (int i2 = ty; i2 < 32; i2 += 8) {
    float acc = 0.f;
    #pragma unroll
    for (int kh = 0; kh < 3; ++kh)
      #pragma unroll
      for (int kw = 0; kw < 3; ++kw)
        acc += wr[kh*3 + kw]*in[i2 + kh][tx + kw];
    ot[i2][tx] = acc;
  }
  __syncthreads();
  ushort* yp  = (ushort*)(y  + (size_t)n*16384);
  ushort* ytp = (ushort*)(yT + (size_t)n*16384);
  for (int idx = threadIdx.x; idx < 512; idx += 256) {
    int row = idx >> 4, c2 = (idx & 15)*2;
    ushort2 u;
    u.x = bfb(ot[row][c2]); u.y = bfb(ot[row][c2 + 1]);
    *(ushort2*)&yp[(size_t)(h0 + row)*128 + w0 + c2] = u;
    ushort2 v;
    v.x = bfb(ot[c2][row]); v.y = bfb(ot[c2 + 1][row]);
    *(ushort2*)&ytp[(size_t)(w0 + row)*128 + h0 + c2] = v;
  }
}

// Fused CCA direction kernel, two barriers, no max-subtract.
// dir=0: src=A -> dstRow, stats sW.  dir=1: src=dst=AT in place, diag mask,
// stats sH.  Output UNNORMALIZED: O[d][p] = sum_c exp(e(p,c)) * v[d][c].
__global__ __launch_bounds__(256) void ccdir_kernel(
    const __bf16* __restrict__ srcRow, __bf16* __restrict__ dstRow,
    __bf16* __restrict__ srcdstCol,
    const __bf16* __restrict__ wtab,
    float* __restrict__ sW, float* __restrict__ sH) {
  // LDS: ys[128][72]b16 (XOR-swizzled chunks) @0 (18432; per-wave out-stage
  // [64][36]b16 = 4608 B aliases it post-B1); ks[128][8] @20480;
  // vs[64][140] @22528 (17920).  Total 40448 -> 4 blocks/CU.
  __shared__ __align__(16) char smem[40448];
  __bf16* ys = (__bf16*)smem;
  __bf16* ks = (__bf16*)(smem + 20480);
  __bf16* vs = (__bf16*)(smem + 22528);

  int t = threadIdx.x;
  int r = blockIdx.x, b = blockIdx.y, dir = blockIdx.z;
  const __bf16* src = dir ? srcdstCol : srcRow;
  __bf16* dst       = dir ? srcdstCol : dstRow;
  float* so         = dir ? sH : sW;
  const ushort* sp = (const ushort*)(src + (size_t)b*1048576 + (size_t)r*128);

  int lane = t & 63, w = t >> 6;
  int l16 = lane & 15, quad = lane >> 4;

  // ---- phase 0: stage Y[c][p] -> ys[p][c-swizzled] + weight frags ----
  {
    int a = t & 15, cp = t >> 4;          // p0 = a*8; channel pair 2cp(+32q)
    ushort* yr = (ushort*)ys;
    #pragma unroll
    for (int q = 0; q < 2; ++q) {
      int c = 2*cp + 32*q;
      uint4 u0 = *(const uint4*)&sp[(size_t)c*16384 + a*8];
      uint4 u1 = *(const uint4*)&sp[(size_t)(c + 1)*16384 + a*8];
      const ushort* p0 = (const ushort*)&u0;
      const ushort* p1 = (const ushort*)&u1;
      int cx = (((c >> 3) ^ a) & 7)*8 + (c & 7);   // swizzle by (p>>3)&7 == a&7
      #pragma unroll
      for (int j = 0; j < 8; ++j) {
        ushort2 uv; uv.x = p0[j]; uv.y = p1[j];
        *(ushort2*)&yr[(a*8 + j)*72 + cx] = uv;
      }
    }
  }
  bf8 a_qk[2], a_wv[4][2];
  #pragma unroll
  for (int s = 0; s < 2; ++s)
    a_qk[s] = *(const bf8*)&wtab[(s*64 + lane)*8];
  #pragma unroll
  for (int m0 = 0; m0 < 4; ++m0)
    #pragma unroll
    for (int s = 0; s < 2; ++s)
      a_wv[m0][s] = *(const bf8*)&wtab[((2 + m0*2 + s)*64 + lane)*8];
  __syncthreads();                      // B0: ys staged

  // ---- phase 1: projections (wave owns p-block [32w, 32w+32)) ----
  f4 z4 = {0.f, 0.f, 0.f, 0.f};
  bf4 zb4;
  #pragma unroll
  for (int j = 0; j < 4; ++j) zb4[j] = (__bf16)0.f;
  bf8 b_ys[2][2];
  #pragma unroll
  for (int nt = 0; nt < 2; ++nt) {
    int p = w*32 + nt*16 + l16;
    int hi = (p >> 3) & 7;
    #pragma unroll
    for (int s = 0; s < 2; ++s)
      b_ys[nt][s] = *(const bf8*)&ys[p*72 + ((s*4 + quad) ^ hi)*8];
  }
  // QK proj: C rows 0-7 = Q (quads 0,1), rows 8-15 = K (quads 2,3).
  // Q == E-step B-frag layout -> keep in regs (bq); K -> ks via one b64.
  bf4 bq[2];
  #pragma unroll
  for (int nt = 0; nt < 2; ++nt) {
    int p = w*32 + nt*16 + l16;
    f4 aqk = z4;
    aqk = MFMA(a_qk[0], b_ys[nt][0], aqk);
    aqk = MFMA(a_qk[1], b_ys[nt][1], aqk);
    bf4 cv;
    #pragma unroll
    for (int rg = 0; rg < 4; ++rg) cv[rg] = (__bf16)aqk[rg];
    if (quad >= 2)
      *(bf4*)&ks[p*8 + (quad & 1)*4] = cv;
    bq[nt] = (quad < 2) ? cv : zb4;
  }
  // V proj SWAPPED: D = Y^T * wv^T = V^T -> lane holds V[d=m0*16+l16]
  // [p = w*32+nt*16+quad*4+rg] -> vs write is one b64 (4 consecutive p).
  #pragma unroll
  for (int m0 = 0; m0 < 4; ++m0)
    #pragma unroll
    for (int nt = 0; nt < 2; ++nt) {
      f4 va = z4;
      va = MFMA(b_ys[nt][0], a_wv[m0][0], va);
      va = MFMA(b_ys[nt][1], a_wv[m0][1], va);
      bf4 vv;
      #pragma unroll
      for (int rg = 0; rg < 4; ++rg) vv[rg] = (__bf16)va[rg];
      *(bf4*)&vs[(m0*16 + l16)*140 + w*32 + nt*16 + quad*4] = vv;
    }
  __syncthreads();                      // B1: ks/vs visible; ys dead

  // ---- barrier-free tail: E^T = MFMA16(K,Q) -> exp2 in-reg -> x16 PV ----
  // E^T C-layout: lane holds E[p=l16-mapped][c=quad*4+rg] == B-frag (pb).
  // PV SWAPPED: acc = MFMA16(pb, av) -> D[p][d]: lane holds
  // O[d=m0*16+l16][p=w*32+nt*16+quad*4+rg] -> b64 out-stage.
  f4 acc[4][2];
  #pragma unroll
  for (int m0 = 0; m0 < 4; ++m0)
    #pragma unroll
    for (int nt = 0; nt < 2; ++nt) acc[m0][nt] = z4;
  float sm[2] = {0.f, 0.f};

  #pragma unroll
  for (int ct = 0; ct < 8; ++ct) {
    bf4 ak = (quad < 2) ? *(const bf4*)&ks[(ct*16 + l16)*8 + quad*4] : zb4;
    bf4 av[4];
    #pragma unroll
    for (int m0 = 0; m0 < 4; ++m0)
      av[m0] = *(const bf4*)&vs[(m0*16 + l16)*140 + ct*16 + quad*4];
    #pragma unroll
    for (int nt = 0; nt < 2; ++nt) {
      f4 e = MFMA16(ak, bq[nt], z4);
      if (dir) {                        // diag mask: c == p
        int pg = w*32 + nt*16 + l16, c0 = ct*16 + quad*4;
        #pragma unroll
        for (int rg = 0; rg < 4; ++rg)
          if (c0 + rg == pg) e[rg] = NEGINF;
      }
      bf4 pb;
      #pragma unroll
      for (int rg = 0; rg < 4; ++rg) {
        float pv = exp2f(e[rg]);        // wq pre-scaled by log2(e)
        sm[nt] += pv;
        pb[rg] = (__bf16)pv;
      }
      #pragma unroll
      for (int m0 = 0; m0 < 4; ++m0)
        acc[m0][nt] = MFMA16(pb, av[m0], acc[m0][nt]);
    }
  }

  // stats: lane holds partial S[p=l16] over c = quad*4+rg (+16ct); reduce quads
  int sb = ((b*128 + r) << 7);
  #pragma unroll
  for (int nt = 0; nt < 2; ++nt) {
    float s2 = sm[nt];
    s2 += __shfl_xor(s2, 16, 64);
    s2 += __shfl_xor(s2, 32, 64);
    if (quad == 0) so[sb + w*32 + nt*16 + l16] = s2;
  }

  // out-stage in own-wave slice of ys (wave-private; post-B1 so ys is dead)
  __bf16* oS = (__bf16*)(smem + 4608*w);   // [64][36] bf16
  #pragma unroll
  for (int m0 = 0; m0 < 4; ++m0)
    #pragma unroll
    for (int nt = 0; nt < 2; ++nt) {
      bf4 ov;
      #pragma unroll
      for (int rg = 0; rg < 4; ++rg) ov[rg] = (__bf16)acc[m0][nt][rg];
      *(bf4*)&oS[(m0*16 + l16)*36 + nt*16 + quad*4] = ov;
    }
  ushort* dp = (ushort*)(dst + (size_t)b*1048576 + (size_t)r*128 + w*32);
  ushort* oSu = (ushort*)oS;
  #pragma unroll
  for (int it = 0; it < 4; ++it) {
    int i = it*64 + lane;
    int d = i >> 2, ch = i & 3;
    uint2 lo  = *(const uint2*)&oSu[d*36 + ch*8];
    uint2 hi2 = *(const uint2*)&oSu[d*36 + ch*8 + 4];
    uint4 uu; uu.x = lo.x; uu.y = lo.y; uu.z = hi2.x; uu.w = hi2.y;
    *(uint4*)&dp[(size_t)d*16384 + ch*8] = uu;
  }
}

// Fused scale+combine:  Bo = gamma*(Bo + oT^T)/(sW+sH) + A.  Optionally
// writes Bo^T into BoT (may alias oT; tile staged to LDS first).
// 16x16 threads, 2-wide x (ushort2/float2 traffic).
__global__ __launch_bounds__(256) void combineT_kernel(
    __bf16* __restrict__ Bo, const __bf16* oT,
    const __bf16* __restrict__ A,
    const float* __restrict__ sW, const float* __restrict__ sH,
    const float* __restrict__ gamma, __bf16* BoT, int writeT) {
  __shared__ float tile[32][33], ts[32][33];
  __shared__ float rt[32][33];
  int tx = threadIdx.x, ty = threadIdx.y;       // 16x16
  int n = blockIdx.z;                           // b*64 + d
  int b = n >> 6;
  int x0 = blockIdx.x*32, y0 = blockIdx.y*32;
  const ushort* ip = (const ushort*)(oT + (size_t)n*16384);
  const float* shp = sH + b*16384;
  for (int i = ty; i < 32; i += 16) {
    ushort2 u = *(const ushort2*)&ip[(size_t)(y0 + i)*128 + x0 + 2*tx];
    tile[i][2*tx]     = (float)*(__bf16*)&u.x;
    tile[i][2*tx + 1] = (float)*(__bf16*)&u.y;
    float2 s2 = *(const float2*)&shp[(y0 + i)*128 + x0 + 2*tx];
    ts[i][2*tx] = s2.x; ts[i][2*tx + 1] = s2.y;
  }
  __syncthreads();
  float g = *gamma;
  for (int i2 = ty; i2 < 32; i2 += 16) {
    int h = x0 + i2, w2 = y0 + 2*tx;
    size_t idx = (size_t)n*16384 + (size_t)h*128 + w2;
    int pix = b*16384 + h*128 + w2;
    float2 swv = *(const float2*)&sW[pix];
    ushort2 bo = *(const ushort2*)((const ushort*)Bo + idx);
    ushort2 aa = *(const ushort2*)((const ushort*)A + idx);
    float inv0 = 1.0f/(swv.x + ts[2*tx][i2]);
    float r0 = g*((float)*(__bf16*)&bo.x + tile[2*tx][i2])*inv0
               + (float)*(__bf16*)&aa.x;
    float inv1 = 1.0f/(swv.y + ts[2*tx + 1][i2]);
    float r1 = g*((float)*(__bf16*)&bo.y + tile[2*tx + 1][i2])*inv1
               + (float)*(__bf16*)&aa.y;
    ushort2 o; o.x = bfb(r0); o.y = bfb(r1);
    *(ushort2*)((ushort*)Bo + idx) = o;
    rt[i2][2*tx] = r0; rt[i2][2*tx + 1] = r1;
  }
  if (writeT) {
    __syncthreads();
    for (int i = ty; i < 32; i += 16) {
      ushort2 o;
      o.x = bfb(rt[2*tx][i]); o.y = bfb(rt[2*tx + 1][i]);
      *(ushort2*)((ushort*)BoT + (size_t)n*16384 +
                  (size_t)(y0 + i)*128 + x0 + 2*tx) = o;
    }
  }
}

// MFMA pointwise 64->64 per (b,r) slice: out[o][p] = sum_c wpw[o][c]*A[c][p].
// SWAPPED MFMA(b_ys, a_w) -> D[p][o]: lane holds out[o=m0*16+l16]
// [p=w*32+nt*16+quad*4+rg] -> f4 b128 out-stage.
__global__ __launch_bounds__(256) void pw_kernel(
    const __bf16* __restrict__ A, const __bf16* __restrict__ ptab,
    float* __restrict__ out) {
  // ys[128][72] swizzled @0 (18432); out-stage [64][36]f32/wave (9216) alias.
  __shared__ __align__(16) char smem[36864];
  __bf16* ys = (__bf16*)smem;
  int t = threadIdx.x;
  int r = blockIdx.x, b = blockIdx.y;
  const ushort* sp = (const ushort*)(A + (size_t)b*1048576 + (size_t)r*128);
  {
    int a = t & 15, cp = t >> 4;
    ushort* yr = (ushort*)ys;
    #pragma unroll
    for (int q = 0; q < 2; ++q) {
      int c = 2*cp + 32*q;
      uint4 u0 = *(const uint4*)&sp[(size_t)c*16384 + a*8];
      uint4 u1 = *(const uint4*)&sp[(size_t)(c + 1)*16384 + a*8];
      const ushort* p0 = (const ushort*)&u0;
      const ushort* p1 = (const ushort*)&u1;
      int cx = (((c >> 3) ^ a) & 7)*8 + (c & 7);
      #pragma unroll
      for (int j = 0; j < 8; ++j) {
        ushort2 uv; uv.x = p0[j]; uv.y = p1[j];
        *(ushort2*)&yr[(a*8 + j)*72 + cx] = uv;
      }
    }
  }
  int lane = t & 63, w = t >> 6;
  int l16 = lane & 15, quad = lane >> 4;
  bf8 a_w[4][2];
  #pragma unroll
  for (int m0 = 0; m0 < 4; ++m0)
    #pragma unroll
    for (int s = 0; s < 2; ++s)
      a_w[m0][s] = *(const bf8*)&ptab[((m0*2 + s)*64 + lane)*8];
  __syncthreads();                     // ys staged
  bf8 b_ys[2][2];
  #pragma unroll
  for (int nt = 0; nt < 2; ++nt) {
    int p = w*32 + nt*16 + l16;
    int hi = (p >> 3) & 7;
    #pragma unroll
    for (int s = 0; s < 2; ++s)
      b_ys[nt][s] = *(const bf8*)&ys[p*72 + ((s*4 + quad) ^ hi)*8];
  }
  __syncthreads();                     // all frag loads done; ys dead
  f4 z4 = {0.f, 0.f, 0.f, 0.f};
  f4 acc[4][2];
  #pragma unroll
  for (int m0 = 0; m0 < 4; ++m0)
    #pragma unroll
    for (int nt = 0; nt < 2; ++nt) {
      f4 a2 = z4;
      a2 = MFMA(b_ys[nt][0], a_w[m0][0], a2);
      a2 = MFMA(b_ys[nt][1], a_w[m0][1], a2);
      acc[m0][nt] = a2;
    }
  float* oS = (float*)(smem + 9216*w);  // [64][36] fp32, wave-local
  #pragma unroll
  for (int m0 = 0; m0 < 4; ++m0)
    #pragma unroll
    for (int nt = 0; nt < 2; ++nt)
      *(f4*)&oS[(m0*16 + l16)*36 + nt*16 + quad*4] = acc[m0][nt];
  float* dp = out + (size_t)b*1048576 + (size_t)r*128 + w*32;
  #pragma unroll
  for (int it = 0; it < 8; ++it) {
    int i = it*64 + lane;
    int d = i >> 3, p4 = i & 7;
    f4 v = *(const f4*)&oS[d*36 + p4*4];
    *(f4*)&dp[(size_t)d*16384 + p4*4] = v;
  }
}

extern "C" void kernel_launch(void* const* d_in, const int* in_sizes, int n_in,
                              void* d_out, int out_size, void* d_ws, size_t ws_size,
                              hipStream_t stream) {
  const float* x     = (const float*)d_in[0];
  const float* wdw   = (const float*)d_in[1];
  const float* wq    = (const float*)d_in[2];
  const float* wk    = (const float*)d_in[3];
  const float* wv    = (const float*)d_in[4];
  const float* gamma = (const float*)d_in[5];
  const float* wpw   = (const float*)d_in[6];
  float* out = (float*)d_out;

  // Workspace: y,z,AT bf16 (16 MB each) + wtab/ptab + 2 fp32 stat planes.
  __bf16* y    = (__bf16*)d_ws;
  __bf16* z    = y + 8388608;
  __bf16* AT   = z + 8388608;
  __bf16* wtab = AT + 8388608;        // 10 frags x 64 lanes x 8 = 5120
  __bf16* ptab = wtab + 5120;         // 8 frags x 64 lanes x 8 = 4096
  float* sW = (float*)(ptab + 4096);
  float* sH = sW + 131072;
  size_t need = (size_t)3*8388608*2 + (5120 + 4096)*2 + (size_t)2*131072*4;
  if (ws_size < need) return;

  dwconv_kernel<<<dim3(4, 4, 512), 256, 0, stream>>>(
      x, wdw, y, AT, wq, wk, wv, wpw, wtab, ptab);

  for (int pass = 0; pass < 2; ++pass) {
    const __bf16* A = pass ? z : y;   // CCA input / residual
    __bf16* Bo      = pass ? y : z;   // CCA output

    ccdir_kernel<<<dim3(128, 8, 2), 256, 0, stream>>>(
        A, Bo, AT, wtab, sW, sH);
    // pass 0: also write Bo^T into AT (next pass's transposed input)
    combineT_kernel<<<dim3(4, 4, 512), dim3(16, 16), 0, stream>>>(
        Bo, AT, A, sW, sH, gamma, AT, pass == 0 ? 1 : 0);
  }

  pw_kernel<<<dim3(128, 8), 256, 0, stream>>>(y, ptab, out);
}